// Round 8
// baseline (394.328 us; speedup 1.0000x reference)
//
#include <hip/hip_runtime.h>
#include <math.h>

using u16 = unsigned short;
using u32 = unsigned int;

typedef __attribute__((ext_vector_type(8))) short short8;   // 8 x bf16 (4 VGPRs)
typedef __attribute__((ext_vector_type(4))) float float4v;  // MFMA C/D

#define S_LEN 4032   // 9*16*28
#define DIM   1536
#define NH    12
#define HD    128
#define F_DIM 9
#define H_DIM 16
#define W_DIM 28
#define NX4 1548288      // S_LEN*DIM/4
#define NW4 589824       // DIM*DIM/4

__device__ __forceinline__ float b2f(u16 v) {
  return __uint_as_float(((u32)v) << 16);
}
__device__ __forceinline__ u16 f2bf(float f) {
  u32 u = __float_as_uint(f);
  u32 r = (u + 0x7FFFu + ((u >> 16) & 1u)) >> 16;  // RNE
  return (u16)r;
}
// pack two floats -> one u32 of two bf16 by truncation, single v_perm_b32.
// P in (0, 2^-3.6]; trunc error <= 2^-8 relative -- inside absmax budget.
__device__ __forceinline__ u32 pack2(float lo, float hi) {
  return __builtin_amdgcn_perm(__float_as_uint(hi), __float_as_uint(lo),
                               0x07060302u);
}

// async global->LDS, 16B per lane; LDS dst must be wave-uniform base + lane*16
__device__ __forceinline__ void gld16(const void* g, void* l) {
  __builtin_amdgcn_global_load_lds(
      (const __attribute__((address_space(1))) void*)g,
      (__attribute__((address_space(3))) void*)l, 16, 0, 0);
}

// ---- cross-quad word exchange: {x,y} = permlane16_swap(permlane32_swap(a,b))
// x = [Aq0,Aq2,Bq0,Bq2] per 16-group, y = [Aq1,Aq3,Bq1,Bq3]
__device__ __forceinline__ void plswap(u32 a, u32 b, u32& x, u32& y, int lane) {
#if __has_builtin(__builtin_amdgcn_permlane32_swap) && __has_builtin(__builtin_amdgcn_permlane16_swap)
  auto t = __builtin_amdgcn_permlane32_swap(a, b, false, false);
  auto u = __builtin_amdgcn_permlane16_swap(t[0], t[1], false, false);
  x = u[0]; y = u[1];
#else
  // fallback: same semantics via shfl_xor + select
  u32 ax = (u32)__shfl_xor((int)a, 32, 64), bx = (u32)__shfl_xor((int)b, 32, 64);
  u32 t0 = (lane & 32) ? bx : a;          // [A.lo, B.lo]
  u32 t1 = (lane & 32) ? b : ax;          // [A.hi, B.hi]
  u32 t0x = (u32)__shfl_xor((int)t0, 16, 64), t1x = (u32)__shfl_xor((int)t1, 16, 64);
  x = (lane & 16) ? t1x : t0;             // [t0.g0, t1.g0, t0.g2, t1.g2]
  y = (lane & 16) ? t1 : t0x;             // [t0.g1, t1.g1, t0.g3, t1.g3]
#endif
}

// ---------------------------------------------------------------------------
// Fused f32->bf16 cast of x, Wq, Wk, Wv, Wo (one launch). float4 in, ushort4 out.
// ---------------------------------------------------------------------------
__global__ void __launch_bounds__(256) cast_all(
    const float* __restrict__ x, const float* __restrict__ wq,
    const float* __restrict__ wk, const float* __restrict__ wv,
    const float* __restrict__ wo,
    u16* __restrict__ xb, u16* __restrict__ wqb,
    u16* __restrict__ wkb, u16* __restrict__ wvb,
    u16* __restrict__ wob)
{
  int i = blockIdx.x * 256 + threadIdx.x;
  const float* s; u16* d; int j;
  if (i < NX4)              { s = x;  d = xb;  j = i; }
  else if (i < NX4 + NW4)   { s = wq; d = wqb; j = i - NX4; }
  else if (i < NX4 + 2*NW4) { s = wk; d = wkb; j = i - NX4 - NW4; }
  else if (i < NX4 + 3*NW4) { s = wv; d = wvb; j = i - NX4 - 2*NW4; }
  else                      { s = wo; d = wob; j = i - NX4 - 3*NW4; }
  const float4 v = ((const float4*)s)[j];
  ushort4 o;
  o.x = f2bf(v.x); o.y = f2bf(v.y); o.z = f2bf(v.z); o.w = f2bf(v.w);
  ((ushort4*)d)[j] = o;
}

// ---------------------------------------------------------------------------
// Fused QKV GEMM (round-7 verified): one block computes Q,K,V for the same
// (m,n) tile. Tile M=128 x N=64 x 3 outputs; 4 waves (2M x 2N). Staging the
// X-tile once for all three weights: 48 MFMAs per 10 gld16 per wave-step,
// af ds_reads shared across z, X HBM traffic /3. LDS 80KB -> 2 blocks/CU.
// XOR swizzle + __syncthreads dbuf identical to the verified gemm_core.
// ---------------------------------------------------------------------------
__global__ void __launch_bounds__(256) gemm_qkv_fused(
    const u16* __restrict__ X,
    const u16* __restrict__ Wq, const u16* __restrict__ Wk, const u16* __restrict__ Wv,
    const float* __restrict__ bq, const float* __restrict__ bk, const float* __restrict__ bv,
    u16* __restrict__ Qb, u16* __restrict__ Kb, u16* __restrict__ Vb)
{
  __shared__ u16 As[2][128 * 64];      // 32 KB
  __shared__ u16 Bs[2][3][64 * 64];    // 48 KB
  const int tid  = threadIdx.x;
  const int wave = tid >> 6, lane = tid & 63;
  const int quad = lane >> 4, l15 = lane & 15;
  const int wm = wave >> 1, wn = wave & 1;
  const int bm = blockIdx.y * 128, bn = blockIdx.x * 64;

  float4v acc[3][4][2] = {};

  const int arow = lane >> 3;                  // 0..7 row within 8-row segment
  const int acol = ((lane & 7) ^ arow) * 8;    // XOR-swizzled source chunk

  // stage A (16 segs) + 3x B (8 segs each) into buffer b at k-offset kt
  auto stage = [&](int b, int kt) {
#pragma unroll
    for (int c = 0; c < 4; ++c) {
      int seg = wave * 4 + c;
      int row = seg * 8 + arow;
      int ga = bm + row; if (ga > S_LEN - 1) ga = S_LEN - 1;  // clamp tail rows
      gld16(&X[(size_t)ga * DIM + kt + acol], &As[b][seg * 512]);
    }
#pragma unroll
    for (int z = 0; z < 3; ++z) {
      const u16* W = (z == 0) ? Wq : (z == 1) ? Wk : Wv;
#pragma unroll
      for (int c = 0; c < 2; ++c) {
        int seg = wave * 2 + c;
        int row = seg * 8 + arow;
        gld16(&W[(size_t)(bn + row) * DIM + kt + acol], &Bs[b][z][seg * 512]);
      }
    }
  };

  stage(0, 0);
  __syncthreads();   // drain tile 0

  int cur = 0;
  for (int kt = 0; kt < DIM; kt += 64) {
    if (kt + 64 < DIM) stage(cur ^ 1, kt + 64);   // prefetch next tile

#pragma unroll
    for (int ks = 0; ks < 64; ks += 32) {
      const int kc = ks >> 3;        // chunk base: 0 or 4
      short8 af[4];
#pragma unroll
      for (int mt = 0; mt < 4; ++mt) {
        const int ra = wm * 64 + mt * 16 + l15;
        af[mt] = *(const short8*)((const char*)As[cur] + ra * 128 + (((kc + quad) ^ (ra & 7)) << 4));
      }
#pragma unroll
      for (int z = 0; z < 3; ++z) {
        short8 bf[2];
#pragma unroll
        for (int nt = 0; nt < 2; ++nt) {
          const int rb = wn * 32 + nt * 16 + l15;
          bf[nt] = *(const short8*)((const char*)Bs[cur][z] + rb * 128 + (((kc + quad) ^ (rb & 7)) << 4));
        }
#pragma unroll
        for (int mt = 0; mt < 4; ++mt)
#pragma unroll
          for (int nt = 0; nt < 2; ++nt)
            acc[z][mt][nt] = __builtin_amdgcn_mfma_f32_16x16x32_bf16(af[mt], bf[nt], acc[z][mt][nt], 0, 0, 0);
      }
    }

    __syncthreads();   // drains prefetch loads + all reads of buf[cur]
    cur ^= 1;
  }

  // epilogue: per z, C row = quad*4+r, col = lane&15
#pragma unroll
  for (int z = 0; z < 3; ++z) {
    u16* O          = (z == 0) ? Qb : (z == 1) ? Kb : Vb;
    const float* bi = (z == 0) ? bq : (z == 1) ? bk : bv;
#pragma unroll
    for (int mt = 0; mt < 4; ++mt) {
      const int row = bm + wm * 64 + mt * 16 + quad * 4;
#pragma unroll
      for (int nt = 0; nt < 2; ++nt) {
        const int col = bn + wn * 32 + nt * 16 + l15;
        const float bv_ = bi[col];
#pragma unroll
        for (int r = 0; r < 4; ++r) {
          float v = acc[z][mt][nt][r] + bv_;
          if (row + r < S_LEN)
            O[(size_t)(row + r) * DIM + col] = f2bf(v);
        }
      }
    }
  }
}

// ---------------------------------------------------------------------------
// GEMM core (round-5 verified): 128x128 tile, 4 waves, BK=64, XOR swizzle,
// __syncthreads double-buffer. Used by gemm_wo.
// ---------------------------------------------------------------------------
template <bool F32OUT>
__device__ __forceinline__ void gemm_core(
    const u16* __restrict__ A, const u16* __restrict__ Bw,
    const float* __restrict__ bias, void* __restrict__ OutV,
    int bm, int bn)
{
  __shared__ u16 As[2][128 * 64];
  __shared__ u16 Bs[2][128 * 64];
  const int tid  = threadIdx.x;
  const int wave = tid >> 6, lane = tid & 63;
  const int quad = lane >> 4, l15 = lane & 15;
  const int wm = wave >> 1, wn = wave & 1;

  float4v acc[4][4] = {};

  const int arow = lane >> 3;                  // 0..7 row within 8-row segment
  const int acol = ((lane & 7) ^ arow) * 8;    // XOR-swizzled source chunk

  auto stage = [&](int b, int kt) {
#pragma unroll
    for (int c = 0; c < 4; ++c) {
      int seg = wave * 4 + c;        // 16 segments of 8 rows x 128B
      int row = seg * 8 + arow;
      int ga = bm + row; if (ga > S_LEN - 1) ga = S_LEN - 1;  // clamp tail rows
      gld16(&A[(size_t)ga * DIM + kt + acol], &As[b][seg * 512]);
      gld16(&Bw[(size_t)(bn + row) * DIM + kt + acol], &Bs[b][seg * 512]);
    }
  };

  stage(0, 0);
  __syncthreads();   // drain tile 0

  int cur = 0;
  for (int kt = 0; kt < DIM; kt += 64) {
    if (kt + 64 < DIM) stage(cur ^ 1, kt + 64);   // prefetch next tile

#pragma unroll
    for (int ks = 0; ks < 64; ks += 32) {
      const int kc = ks >> 3;        // chunk base: 0 or 4
      short8 af[4], bf[4];
#pragma unroll
      for (int mt = 0; mt < 4; ++mt) {
        const int ra = wm * 64 + mt * 16 + l15;
        af[mt] = *(const short8*)((const char*)As[cur] + ra * 128 + (((kc + quad) ^ (ra & 7)) << 4));
      }
#pragma unroll
      for (int nt = 0; nt < 4; ++nt) {
        const int rb = wn * 64 + nt * 16 + l15;
        bf[nt] = *(const short8*)((const char*)Bs[cur] + rb * 128 + (((kc + quad) ^ (rb & 7)) << 4));
      }
#pragma unroll
      for (int mt = 0; mt < 4; ++mt)
#pragma unroll
        for (int nt = 0; nt < 4; ++nt)
          acc[mt][nt] = __builtin_amdgcn_mfma_f32_16x16x32_bf16(af[mt], bf[nt], acc[mt][nt], 0, 0, 0);
    }

    __syncthreads();   // drains prefetch loads + all reads of buf[cur]
    cur ^= 1;
  }

  // epilogue: C row = quad*4+r, col = lane&15
#pragma unroll
  for (int mt = 0; mt < 4; ++mt) {
    const int row = bm + wm * 64 + mt * 16 + quad * 4;
#pragma unroll
    for (int nt = 0; nt < 4; ++nt) {
      const int col = bn + wn * 64 + nt * 16 + l15;
      const float bv = bias[col];
#pragma unroll
      for (int r = 0; r < 4; ++r) {
        float v = acc[mt][nt][r] + bv;
        if (row + r < S_LEN) {
          if (F32OUT) ((float*)OutV)[(size_t)(row + r) * DIM + col] = v;
          else        ((u16*)OutV)[(size_t)(row + r) * DIM + col] = f2bf(v);
        }
      }
    }
  }
}

__global__ void __launch_bounds__(256) gemm_wo(
    const u16* __restrict__ A, const u16* __restrict__ Wo,
    const float* __restrict__ bo, float* __restrict__ Out)
{
  gemm_core<true>(A, Wo, bo, Out, blockIdx.y * 128, blockIdx.x * 128);
}

// ---------------------------------------------------------------------------
// RMS (sumsq computed in-block over full 1536) + 3-axis RoPE, in place on Q,K.
// Vectorized: u32 (bf16x2) loads/stores -- pairs are adjacent and 4B aligned.
// ---------------------------------------------------------------------------
__global__ void __launch_bounds__(256) rms_rope(
    u16* Q, u16* K,
    const float* __restrict__ gq, const float* __restrict__ gk,
    const float* __restrict__ cf, const float* __restrict__ sf,
    const float* __restrict__ ch, const float* __restrict__ sh,
    const float* __restrict__ cw, const float* __restrict__ sw)
{
  __shared__ float red[2][4];
  const int s = blockIdx.x;
  const int t = threadIdx.x;
  const int wave = t >> 6, lane = t & 63;
  const size_t rowb = (size_t)s * DIM + t * 6;   // element index, even

  u32* q32 = (u32*)(Q + rowb);
  u32* k32 = (u32*)(K + rowb);
  u32 qw[3], kw[3];
#pragma unroll
  for (int j = 0; j < 3; ++j) { qw[j] = q32[j]; kw[j] = k32[j]; }

  float sq = 0.f, sk = 0.f;
#pragma unroll
  for (int j = 0; j < 3; ++j) {
    float a0 = b2f((u16)qw[j]), a1 = b2f((u16)(qw[j] >> 16));
    float b0 = b2f((u16)kw[j]), b1 = b2f((u16)(kw[j] >> 16));
    sq += a0 * a0 + a1 * a1;
    sk += b0 * b0 + b1 * b1;
  }
#pragma unroll
  for (int m = 1; m < 64; m <<= 1) {
    sq += __shfl_xor(sq, m, 64);
    sk += __shfl_xor(sk, m, 64);
  }
  if (lane == 0) { red[0][wave] = sq; red[1][wave] = sk; }
  __syncthreads();
  const float tq = red[0][0] + red[0][1] + red[0][2] + red[0][3];
  const float tk = red[1][0] + red[1][1] + red[1][2] + red[1][3];
  const float scq = rsqrtf(tq * (1.0f / DIM) + 1e-6f);
  const float sck = rsqrtf(tk * (1.0f / DIM) + 1e-6f);

  const int f  = s / (H_DIM * W_DIM);
  const int hh = (s / W_DIM) % H_DIM;
  const int w  = s % W_DIM;

#pragma unroll
  for (int j = 0; j < 3; ++j) {
    const int pi = t * 3 + j;       // global pair index 0..767
    const int c = pi & 63;          // rotary pair within head (C=64)
    float co, si;
    if (c < 22)      { co = cf[f * 22 + c];        si = sf[f * 22 + c]; }
    else if (c < 43) { co = ch[hh * 21 + c - 22];  si = sh[hh * 21 + c - 22]; }
    else             { co = cw[w * 21 + c - 43];   si = sw[w * 21 + c - 43]; }
    const int gi = 2 * pi;          // == head*128 + 2*c
    const float2 gqv = *(const float2*)&gq[gi];
    const float2 gkv = *(const float2*)&gk[gi];
    {
      float e = b2f((u16)qw[j])         * scq * gqv.x;
      float o = b2f((u16)(qw[j] >> 16)) * scq * gqv.y;
      q32[j] = (u32)f2bf(e * co - o * si) | ((u32)f2bf(e * si + o * co) << 16);
    }
    {
      float e = b2f((u16)kw[j])         * sck * gkv.x;
      float o = b2f((u16)(kw[j] >> 16)) * sck * gkv.y;
      k32[j] = (u32)f2bf(e * co - o * si) | ((u32)f2bf(e * si + o * co) << 16);
    }
  }
}

// ---------------------------------------------------------------------------
// V transpose: Vt[d][s] = V[s][d]  (bf16), 64x64 LDS tiles.
// ---------------------------------------------------------------------------
__global__ void __launch_bounds__(256) transpose_v(
    const u16* __restrict__ V, u16* __restrict__ Vt)
{
  __shared__ u16 tile[64][65];
  const int s0 = blockIdx.x * 64, d0 = blockIdx.y * 64;
  const int t = threadIdx.x;
#pragma unroll
  for (int i = 0; i < 16; ++i) {
    int idx = t + i * 256; int rr = idx >> 6, cc = idx & 63;
    tile[rr][cc] = V[(size_t)(s0 + rr) * DIM + d0 + cc];
  }
  __syncthreads();
#pragma unroll
  for (int i = 0; i < 16; ++i) {
    int idx = t + i * 256; int rr = idx >> 6, cc = idx & 63;
    Vt[(size_t)(d0 + rr) * S_LEN + s0 + cc] = tile[cc][rr];
  }
}

// ---------------------------------------------------------------------------
// Flash attention v10: nsplit 2->4 for occupancy.
// Round-7 counters: MfmaUtil 38.8 == VALUBusy 38.8, occupancy 19% (2
// blocks/CU) -- neither pipe saturated; the barrier-locked QK->SM->PV chain
// needs more independent blocks per CU to interleave. VGPR=128 fits 4
// waves/SIMD exactly (512/128); LDS 32KB/block -> 4 blocks/CU = 128KB.
// Grid 1008 = 8 XCD x 126 (same decode algebra); klen=1024. This re-runs
// round-1's nsplit=4 WITHOUT the spill confound (VGPR was 64 then, 128 now).
// Runtime ws_size guard keeps the nsplit=2 fallback.
// Everything else: mt=3 (48 q/wave), static-max softmax, permlane P-path,
// gld16 staging, XOR swizzles -- all carried verified.
// ---------------------------------------------------------------------------
__global__ void __launch_bounds__(256, 2) attn_kernel(
    const u16* __restrict__ rq, const u16* __restrict__ rk,
    const u16* __restrict__ vt,
    u16* __restrict__ po, float* __restrict__ pl, int klen)
{
  __shared__ u16 Ks[64 * 128];       // 16 KB  [key][d]; slot(kr,kc) holds chunk kc^(kr&15)
  __shared__ u16 Vs[128 * 64];       // 16 KB  [d][key]; slot(vd,vc) holds chunk vc^(vd&7)

  // decode: grid = 8 xcd * (21 * 3*nsplit/2); slice pinned to XCD = id&7
  const int id    = blockIdx.x;
  const int xcd   = id & 7;
  const int rest  = id >> 3;          // 0..(21*nslice/8 - 1)
  const int band  = rest / 21;        // 0..(nslice/8 - 1)
  const int slot  = rest - band * 21; // q-block 0..20
  const int slice = band * 8 + xcd;   // 0..(NH*nsplit - 1)
  const int h     = slice % NH;
  const int split = slice / NH;
  const int k_begin = split * klen;
  const int k_end   = (k_begin + klen < S_LEN) ? (k_begin + klen) : S_LEN;
  const int qb = slot * 192;
  const int tid = threadIdx.x, wave = tid >> 6, lane = tid & 63;
  const int quad = lane >> 4, l15 = lane & 15;
  const int q0 = qb + wave * 48;

  const int kr_l   = (lane >> 4);          // K row within 4-row seg
  const int kc_l   = lane & 15;
  const int vdr_l  = (lane >> 3);          // V d-row within 8-row seg
  const int vc_l   = lane & 7;

  // Q fragments (B-operand: n=query=l15, k=d=quad*8+j)
  short8 qf[3][4];
#pragma unroll
  for (int mt = 0; mt < 3; ++mt) {
    int row = q0 + mt * 16 + l15; if (row > S_LEN - 1) row = S_LEN - 1;
#pragma unroll
    for (int c = 0; c < 4; ++c)
      qf[mt][c] = *(const short8*)&rq[(size_t)row * DIM + h * HD + c * 32 + quad * 8];
  }

  float4v o[3][8] = {};                 // O^T: row=d(quad*4+r), col=query(l15)
  float l_[3] = {0.f, 0.f, 0.f};        // per-lane partial; reduced at epilogue

  const float SC = 0.08838834764831845f * 1.4426950408889634f;  // rsqrt(128)*log2(e)
  const float M0 = 20.0f;  // static max (log2 domain); hard bound is 16.4

  // ---- prologue: stage K(k_begin) ----
#pragma unroll
  for (int c = 0; c < 4; ++c) {
    const int seg = wave * 4 + c;
    const int kr = seg * 4 + kr_l;
    gld16(&rk[(size_t)(k_begin + kr) * DIM + h * HD + ((kc_l ^ (kr & 15)) << 3)],
          &Ks[seg * 512]);
  }
  __syncthreads();   // drain K(0)

  for (int kt = k_begin; kt < k_end; kt += 64) {
    // ---- issue V(kt): overlapped with QK + softmax below ----
#pragma unroll
    for (int c = 0; c < 4; ++c) {
      const int seg = wave * 4 + c;
      const int vd = seg * 8 + vdr_l;
      gld16(&vt[(size_t)(h * HD + vd) * S_LEN + kt + ((vc_l ^ (vd & 7)) << 3)],
            &Vs[seg * 512]);
    }

    short8 pf[3][2];   // [mt][ko]: PV B-operand fragments

    // ---- two 32-key halves: QK (24 MFMA) -> exp -> pack -> permlane ----
#pragma unroll
    for (int half = 0; half < 2; ++half) {
      float4v sc[3][2] = {};   // [mt][nth]
      __builtin_amdgcn_s_setprio(1);
#pragma unroll
      for (int nth = 0; nth < 2; ++nth) {
        const int krow = (half * 2 + nth) * 16 + l15;
#pragma unroll
        for (int c = 0; c < 4; ++c) {
          const short8 kf = *(const short8*)((char*)Ks + krow * 256 + (((c * 4 + quad) ^ l15) << 4));
#pragma unroll
          for (int mt = 0; mt < 3; ++mt)
            sc[mt][nth] = __builtin_amdgcn_mfma_f32_16x16x32_bf16(kf, qf[mt][c], sc[mt][nth], 0, 0, 0);
        }
      }
      __builtin_amdgcn_s_setprio(0);

#pragma unroll
      for (int mt = 0; mt < 3; ++mt) {
        u32 W[2][2];
#pragma unroll
        for (int nth = 0; nth < 2; ++nth) {
          const float p0 = __builtin_amdgcn_exp2f(fmaf(sc[mt][nth][0], SC, -M0));
          const float p1 = __builtin_amdgcn_exp2f(fmaf(sc[mt][nth][1], SC, -M0));
          const float p2 = __builtin_amdgcn_exp2f(fmaf(sc[mt][nth][2], SC, -M0));
          const float p3 = __builtin_amdgcn_exp2f(fmaf(sc[mt][nth][3], SC, -M0));
          l_[mt] += (p0 + p1) + (p2 + p3);
          W[nth][0] = pack2(p0, p1);
          W[nth][1] = pack2(p2, p3);
        }
        u32 w0, w1, w2, w3;
        plswap(W[0][0], W[1][0], w0, w2, lane);   // j2=0, j2=2 words
        plswap(W[0][1], W[1][1], w1, w3, lane);   // j2=1, j2=3 words
        union { u32 w[4]; short8 s; } cv;
        cv.w[0] = w0; cv.w[1] = w1; cv.w[2] = w2; cv.w[3] = w3;
        pf[mt][half] = cv.s;
      }
    }

    __syncthreads();   // B1: drains V(kt); all waves done reading Ks

    // ---- issue K(kt+64): overlapped with PV below ----
    if (kt + 64 < k_end) {
#pragma unroll
      for (int c = 0; c < 4; ++c) {
        const int seg = wave * 4 + c;
        const int kr = seg * 4 + kr_l;
        gld16(&rk[(size_t)(kt + 64 + kr) * DIM + h * HD + ((kc_l ^ (kr & 15)) << 3)],
              &Ks[seg * 512]);
      }
    }

    // ---- O^T += V^T · P^T : 48 MFMAs (vf shared across mt) ----
    __builtin_amdgcn_s_setprio(1);
#pragma unroll
    for (int dt = 0; dt < 8; ++dt) {
      const int drow = dt * 16 + l15;
#pragma unroll
      for (int ko = 0; ko < 2; ++ko) {
        const short8 vf = *(const short8*)((char*)Vs + drow * 128 + (((ko * 4 + quad) ^ (l15 & 7)) << 4));
#pragma unroll
        for (int mt = 0; mt < 3; ++mt)
          o[mt][dt] = __builtin_amdgcn_mfma_f32_16x16x32_bf16(vf, pf[mt][ko], o[mt][dt], 0, 0, 0);
      }
    }
    __builtin_amdgcn_s_setprio(0);

    __syncthreads();   // B2: drains K(kt+64); all waves done reading Vs
  }

  // ---- epilogue: reduce l across quads; unnormalized partial o + l ----
#pragma unroll
  for (int mt = 0; mt < 3; ++mt) {
    float t = l_[mt];
    t += __shfl_xor(t, 16, 64);
    t += __shfl_xor(t, 32, 64);
    l_[mt] = t;
  }
#pragma unroll
  for (int mt = 0; mt < 3; ++mt) {
    const int q = q0 + mt * 16 + l15;
    const bool valid = q < S_LEN;
    const size_t rbase = ((size_t)(split * NH + h) * S_LEN + q) * HD;
#pragma unroll
    for (int dt = 0; dt < 8; ++dt) {
      if (valid) {
        ushort4 pk;
        pk.x = f2bf(o[mt][dt][0]); pk.y = f2bf(o[mt][dt][1]);
        pk.z = f2bf(o[mt][dt][2]); pk.w = f2bf(o[mt][dt][3]);
        *(ushort4*)&po[rbase + dt * 16 + quad * 4] = pk;
      }
    }
    if (quad == 0 && valid)
      pl[(size_t)(split * NH + h) * S_LEN + q] = l_[mt];
  }
}

// ---------------------------------------------------------------------------
// Merge nsplit ksplit partials (shared static max -> plain sums).
// One wave per (h,q) row, 2 d-elems per lane.
// ---------------------------------------------------------------------------
__global__ void __launch_bounds__(256) attn_merge(
    const u16* __restrict__ po, const float* __restrict__ pl,
    u16* __restrict__ ao, int nsplit)
{
  const int gw = (blockIdx.x * 256 + threadIdx.x) >> 6;  // (h,q) row id
  const int lane = threadIdx.x & 63;
  const int h = gw / S_LEN;
  const int q = gw - h * S_LEN;
  float den = 0.f, a0 = 0.f, a1 = 0.f;
  for (int s = 0; s < nsplit; ++s) {
    const size_t r = (size_t)(s * NH + h) * S_LEN + q;
    den += pl[r];
    const ushort2 v = *(const ushort2*)&po[r * HD + lane * 2];
    a0 += b2f(v.x); a1 += b2f(v.y);
  }
  const float inv = (den > 0.f) ? (1.0f / den) : 0.f;
  ushort2 out;
  out.x = f2bf(a0 * inv);
  out.y = f2bf(a1 * inv);
  *(ushort2*)&ao[(size_t)q * DIM + h * HD + lane * 2] = out;
}

// ---------------------------------------------------------------------------
extern "C" void kernel_launch(void* const* d_in, const int* in_sizes, int n_in,
                              void* d_out, int out_size, void* d_ws, size_t ws_size,
                              hipStream_t stream) {
  const float* x  = (const float*)d_in[0];
  const float* Wq = (const float*)d_in[1];
  const float* bq = (const float*)d_in[2];
  const float* Wk = (const float*)d_in[3];
  const float* bk = (const float*)d_in[4];
  const float* Wv = (const float*)d_in[5];
  const float* bv = (const float*)d_in[6];
  const float* Wo = (const float*)d_in[7];
  const float* bo = (const float*)d_in[8];
  const float* gq = (const float*)d_in[9];
  const float* gk = (const float*)d_in[10];
  const float* cf = (const float*)d_in[11];
  const float* sf = (const float*)d_in[12];
  const float* ch = (const float*)d_in[13];
  const float* sh = (const float*)d_in[14];
  const float* cw = (const float*)d_in[15];
  const float* sw = (const float*)d_in[16];

  char* ws = (char*)d_ws;
  const size_t sz  = (size_t)S_LEN * DIM * 2;  // 12.39 MB per bf16 activation
  const size_t wsz = (size_t)DIM * DIM * 2;    // 4.72 MB per bf16 weight
  u16* Xb  = (u16*)(ws);               // x bf16; reused as Vt after gemm_qkv
  u16* Qb  = (u16*)(ws + sz);          // becomes rq after rms_rope; reused as Ao
  u16* Kb  = (u16*)(ws + 2 * sz);      // becomes rk
  u16* Vb  = (u16*)(ws + 3 * sz);
  u16* Wqb = (u16*)(ws + 4 * sz);      // dead after gemm_qkv
  u16* Wkb = (u16*)(ws + 4 * sz + wsz);
  u16* Wvb = (u16*)(ws + 4 * sz + 2 * wsz);

  // ksplit partials overlay Wqb..Wvb (dead after gemm_qkv_fused); Wo-bf16
  // lives beyond the partial region.
  // nsplit=4: 4sz + 4*(po_one+pl_one) + wsz = 104.6 MB (round-1 verified fit);
  // fallback nsplit=2: 79.5 MB.
  const size_t po_one = (size_t)NH * S_LEN * HD * 2;   // 12.39 MB per split
  const size_t pl_one = (size_t)NH * S_LEN * 4;        // 193.5 KB per split
  const size_t need4  = 4 * sz + 4 * (po_one + pl_one) + wsz;
  const int nsplit = (ws_size >= need4) ? 4 : 2;
  const int klen   = (nsplit == 4) ? 1024 : 2048;      // 64-aligned k-split
  char* pbase = ws + 4 * sz;
  u16*   po = (u16*)pbase;
  float* pl = (float*)(pbase + (size_t)nsplit * po_one);
  u16* Wob = (u16*)(ws + 4 * sz + (size_t)nsplit * (po_one + pl_one));
  u16* Vt  = Xb;
  u16* Ao  = Qb;  // rq is dead after attn_kernel; merge writes here

  cast_all<<<(NX4 + 4 * NW4) / 256, 256, 0, stream>>>(
      x, Wq, Wk, Wv, Wo, Xb, Wqb, Wkb, Wvb, Wob);

  gemm_qkv_fused<<<dim3(24, 32), 256, 0, stream>>>(
      Xb, Wqb, Wkb, Wvb, bq, bk, bv, Qb, Kb, Vb);

  rms_rope<<<S_LEN, 256, 0, stream>>>(Qb, Kb, gq, gk, cf, sf, ch, sh, cw, sw);
  transpose_v<<<dim3(63, 24), 256, 0, stream>>>(Vb, Vt);
  attn_kernel<<<252 * nsplit, 256, 0, stream>>>(Qb, Kb, Vt, po, pl, klen);
  attn_merge<<<(NH * S_LEN) / 4, 256, 0, stream>>>(po, pl, Ao, nsplit);
  gemm_wo<<<dim3(12, 32), 256, 0, stream>>>(Ao, Wob, bo, (float*)d_out);
}

// Round 9
// 377.989 us; speedup vs baseline: 1.0432x; 1.0432x over previous
//
#include <hip/hip_runtime.h>
#include <math.h>

using u16 = unsigned short;
using u32 = unsigned int;

typedef __attribute__((ext_vector_type(8))) short short8;   // 8 x bf16 (4 VGPRs)
typedef __attribute__((ext_vector_type(4))) float float4v;  // MFMA C/D

#define S_LEN 4032   // 9*16*28
#define DIM   1536
#define NH    12
#define HD    128
#define F_DIM 9
#define H_DIM 16
#define W_DIM 28
#define NX4 1548288      // S_LEN*DIM/4
#define NW4 589824       // DIM*DIM/4

__device__ __forceinline__ float b2f(u16 v) {
  return __uint_as_float(((u32)v) << 16);
}
__device__ __forceinline__ u16 f2bf(float f) {
  u32 u = __float_as_uint(f);
  u32 r = (u + 0x7FFFu + ((u >> 16) & 1u)) >> 16;  // RNE
  return (u16)r;
}
// pack two floats -> one u32 of two bf16 by truncation, single v_perm_b32.
// P in (0, 2^-3.6]; trunc error <= 2^-8 relative -- inside absmax budget.
__device__ __forceinline__ u32 pack2(float lo, float hi) {
  return __builtin_amdgcn_perm(__float_as_uint(hi), __float_as_uint(lo),
                               0x07060302u);
}

// async global->LDS, 16B per lane; LDS dst must be wave-uniform base + lane*16
__device__ __forceinline__ void gld16(const void* g, void* l) {
  __builtin_amdgcn_global_load_lds(
      (const __attribute__((address_space(1))) void*)g,
      (__attribute__((address_space(3))) void*)l, 16, 0, 0);
}

// ---- cross-quad word exchange: {x,y} = permlane16_swap(permlane32_swap(a,b))
// x = [Aq0,Aq2,Bq0,Bq2] per 16-group, y = [Aq1,Aq3,Bq1,Bq3]
__device__ __forceinline__ void plswap(u32 a, u32 b, u32& x, u32& y, int lane) {
#if __has_builtin(__builtin_amdgcn_permlane32_swap) && __has_builtin(__builtin_amdgcn_permlane16_swap)
  auto t = __builtin_amdgcn_permlane32_swap(a, b, false, false);
  auto u = __builtin_amdgcn_permlane16_swap(t[0], t[1], false, false);
  x = u[0]; y = u[1];
#else
  // fallback: same semantics via shfl_xor + select
  u32 ax = (u32)__shfl_xor((int)a, 32, 64), bx = (u32)__shfl_xor((int)b, 32, 64);
  u32 t0 = (lane & 32) ? bx : a;          // [A.lo, B.lo]
  u32 t1 = (lane & 32) ? b : ax;          // [A.hi, B.hi]
  u32 t0x = (u32)__shfl_xor((int)t0, 16, 64), t1x = (u32)__shfl_xor((int)t1, 16, 64);
  x = (lane & 16) ? t1x : t0;             // [t0.g0, t1.g0, t0.g2, t1.g2]
  y = (lane & 16) ? t1 : t0x;             // [t0.g1, t1.g1, t0.g3, t1.g3]
#endif
}

// ---------------------------------------------------------------------------
// Fused f32->bf16 cast of x, Wq, Wk, Wv, Wo (one launch). float4 in, ushort4 out.
// ---------------------------------------------------------------------------
__global__ void __launch_bounds__(256) cast_all(
    const float* __restrict__ x, const float* __restrict__ wq,
    const float* __restrict__ wk, const float* __restrict__ wv,
    const float* __restrict__ wo,
    u16* __restrict__ xb, u16* __restrict__ wqb,
    u16* __restrict__ wkb, u16* __restrict__ wvb,
    u16* __restrict__ wob)
{
  int i = blockIdx.x * 256 + threadIdx.x;
  const float* s; u16* d; int j;
  if (i < NX4)              { s = x;  d = xb;  j = i; }
  else if (i < NX4 + NW4)   { s = wq; d = wqb; j = i - NX4; }
  else if (i < NX4 + 2*NW4) { s = wk; d = wkb; j = i - NX4 - NW4; }
  else if (i < NX4 + 3*NW4) { s = wv; d = wvb; j = i - NX4 - 2*NW4; }
  else                      { s = wo; d = wob; j = i - NX4 - 3*NW4; }
  const float4 v = ((const float4*)s)[j];
  ushort4 o;
  o.x = f2bf(v.x); o.y = f2bf(v.y); o.z = f2bf(v.z); o.w = f2bf(v.w);
  ((ushort4*)d)[j] = o;
}

// ---------------------------------------------------------------------------
// Fused QKV GEMM (round-7 verified): one block computes Q,K,V for the same
// (m,n) tile. Tile M=128 x N=64 x 3 outputs; 4 waves (2M x 2N). Staging the
// X-tile once for all three weights: 48 MFMAs per 10 gld16 per wave-step,
// af ds_reads shared across z, X HBM traffic /3. LDS 80KB -> 2 blocks/CU.
// XOR swizzle + __syncthreads dbuf identical to the verified gemm_core.
// ---------------------------------------------------------------------------
__global__ void __launch_bounds__(256) gemm_qkv_fused(
    const u16* __restrict__ X,
    const u16* __restrict__ Wq, const u16* __restrict__ Wk, const u16* __restrict__ Wv,
    const float* __restrict__ bq, const float* __restrict__ bk, const float* __restrict__ bv,
    u16* __restrict__ Qb, u16* __restrict__ Kb, u16* __restrict__ Vb)
{
  __shared__ u16 As[2][128 * 64];      // 32 KB
  __shared__ u16 Bs[2][3][64 * 64];    // 48 KB
  const int tid  = threadIdx.x;
  const int wave = tid >> 6, lane = tid & 63;
  const int quad = lane >> 4, l15 = lane & 15;
  const int wm = wave >> 1, wn = wave & 1;
  const int bm = blockIdx.y * 128, bn = blockIdx.x * 64;

  float4v acc[3][4][2] = {};

  const int arow = lane >> 3;                  // 0..7 row within 8-row segment
  const int acol = ((lane & 7) ^ arow) * 8;    // XOR-swizzled source chunk

  // stage A (16 segs) + 3x B (8 segs each) into buffer b at k-offset kt
  auto stage = [&](int b, int kt) {
#pragma unroll
    for (int c = 0; c < 4; ++c) {
      int seg = wave * 4 + c;
      int row = seg * 8 + arow;
      int ga = bm + row; if (ga > S_LEN - 1) ga = S_LEN - 1;  // clamp tail rows
      gld16(&X[(size_t)ga * DIM + kt + acol], &As[b][seg * 512]);
    }
#pragma unroll
    for (int z = 0; z < 3; ++z) {
      const u16* W = (z == 0) ? Wq : (z == 1) ? Wk : Wv;
#pragma unroll
      for (int c = 0; c < 2; ++c) {
        int seg = wave * 2 + c;
        int row = seg * 8 + arow;
        gld16(&W[(size_t)(bn + row) * DIM + kt + acol], &Bs[b][z][seg * 512]);
      }
    }
  };

  stage(0, 0);
  __syncthreads();   // drain tile 0

  int cur = 0;
  for (int kt = 0; kt < DIM; kt += 64) {
    if (kt + 64 < DIM) stage(cur ^ 1, kt + 64);   // prefetch next tile

#pragma unroll
    for (int ks = 0; ks < 64; ks += 32) {
      const int kc = ks >> 3;        // chunk base: 0 or 4
      short8 af[4];
#pragma unroll
      for (int mt = 0; mt < 4; ++mt) {
        const int ra = wm * 64 + mt * 16 + l15;
        af[mt] = *(const short8*)((const char*)As[cur] + ra * 128 + (((kc + quad) ^ (ra & 7)) << 4));
      }
#pragma unroll
      for (int z = 0; z < 3; ++z) {
        short8 bf[2];
#pragma unroll
        for (int nt = 0; nt < 2; ++nt) {
          const int rb = wn * 32 + nt * 16 + l15;
          bf[nt] = *(const short8*)((const char*)Bs[cur][z] + rb * 128 + (((kc + quad) ^ (rb & 7)) << 4));
        }
#pragma unroll
        for (int mt = 0; mt < 4; ++mt)
#pragma unroll
          for (int nt = 0; nt < 2; ++nt)
            acc[z][mt][nt] = __builtin_amdgcn_mfma_f32_16x16x32_bf16(af[mt], bf[nt], acc[z][mt][nt], 0, 0, 0);
      }
    }

    __syncthreads();   // drains prefetch loads + all reads of buf[cur]
    cur ^= 1;
  }

  // epilogue: per z, C row = quad*4+r, col = lane&15
#pragma unroll
  for (int z = 0; z < 3; ++z) {
    u16* O          = (z == 0) ? Qb : (z == 1) ? Kb : Vb;
    const float* bi = (z == 0) ? bq : (z == 1) ? bk : bv;
#pragma unroll
    for (int mt = 0; mt < 4; ++mt) {
      const int row = bm + wm * 64 + mt * 16 + quad * 4;
#pragma unroll
      for (int nt = 0; nt < 2; ++nt) {
        const int col = bn + wn * 32 + nt * 16 + l15;
        const float bv_ = bi[col];
#pragma unroll
        for (int r = 0; r < 4; ++r) {
          float v = acc[z][mt][nt][r] + bv_;
          if (row + r < S_LEN)
            O[(size_t)(row + r) * DIM + col] = f2bf(v);
        }
      }
    }
  }
}

// ---------------------------------------------------------------------------
// GEMM core (round-5 verified): 128x128 tile, 4 waves, BK=64, XOR swizzle,
// __syncthreads double-buffer. Used by gemm_wo.
// ---------------------------------------------------------------------------
template <bool F32OUT>
__device__ __forceinline__ void gemm_core(
    const u16* __restrict__ A, const u16* __restrict__ Bw,
    const float* __restrict__ bias, void* __restrict__ OutV,
    int bm, int bn)
{
  __shared__ u16 As[2][128 * 64];
  __shared__ u16 Bs[2][128 * 64];
  const int tid  = threadIdx.x;
  const int wave = tid >> 6, lane = tid & 63;
  const int quad = lane >> 4, l15 = lane & 15;
  const int wm = wave >> 1, wn = wave & 1;

  float4v acc[4][4] = {};

  const int arow = lane >> 3;                  // 0..7 row within 8-row segment
  const int acol = ((lane & 7) ^ arow) * 8;    // XOR-swizzled source chunk

  auto stage = [&](int b, int kt) {
#pragma unroll
    for (int c = 0; c < 4; ++c) {
      int seg = wave * 4 + c;        // 16 segments of 8 rows x 128B
      int row = seg * 8 + arow;
      int ga = bm + row; if (ga > S_LEN - 1) ga = S_LEN - 1;  // clamp tail rows
      gld16(&A[(size_t)ga * DIM + kt + acol], &As[b][seg * 512]);
      gld16(&Bw[(size_t)(bn + row) * DIM + kt + acol], &Bs[b][seg * 512]);
    }
  };

  stage(0, 0);
  __syncthreads();   // drain tile 0

  int cur = 0;
  for (int kt = 0; kt < DIM; kt += 64) {
    if (kt + 64 < DIM) stage(cur ^ 1, kt + 64);   // prefetch next tile

#pragma unroll
    for (int ks = 0; ks < 64; ks += 32) {
      const int kc = ks >> 3;        // chunk base: 0 or 4
      short8 af[4], bf[4];
#pragma unroll
      for (int mt = 0; mt < 4; ++mt) {
        const int ra = wm * 64 + mt * 16 + l15;
        af[mt] = *(const short8*)((const char*)As[cur] + ra * 128 + (((kc + quad) ^ (ra & 7)) << 4));
      }
#pragma unroll
      for (int nt = 0; nt < 4; ++nt) {
        const int rb = wn * 64 + nt * 16 + l15;
        bf[nt] = *(const short8*)((const char*)Bs[cur] + rb * 128 + (((kc + quad) ^ (rb & 7)) << 4));
      }
#pragma unroll
      for (int mt = 0; mt < 4; ++mt)
#pragma unroll
        for (int nt = 0; nt < 4; ++nt)
          acc[mt][nt] = __builtin_amdgcn_mfma_f32_16x16x32_bf16(af[mt], bf[nt], acc[mt][nt], 0, 0, 0);
    }

    __syncthreads();   // drains prefetch loads + all reads of buf[cur]
    cur ^= 1;
  }

  // epilogue: C row = quad*4+r, col = lane&15
#pragma unroll
  for (int mt = 0; mt < 4; ++mt) {
    const int row = bm + wm * 64 + mt * 16 + quad * 4;
#pragma unroll
    for (int nt = 0; nt < 4; ++nt) {
      const int col = bn + wn * 64 + nt * 16 + l15;
      const float bv = bias[col];
#pragma unroll
      for (int r = 0; r < 4; ++r) {
        float v = acc[mt][nt][r] + bv;
        if (row + r < S_LEN) {
          if (F32OUT) ((float*)OutV)[(size_t)(row + r) * DIM + col] = v;
          else        ((u16*)OutV)[(size_t)(row + r) * DIM + col] = f2bf(v);
        }
      }
    }
  }
}

__global__ void __launch_bounds__(256) gemm_wo(
    const u16* __restrict__ A, const u16* __restrict__ Wo,
    const float* __restrict__ bo, float* __restrict__ Out)
{
  gemm_core<true>(A, Wo, bo, Out, blockIdx.y * 128, blockIdx.x * 128);
}

// ---------------------------------------------------------------------------
// RMS (sumsq computed in-block over full 1536) + 3-axis RoPE, in place on Q,K.
// Vectorized: u32 (bf16x2) loads/stores -- pairs are adjacent and 4B aligned.
// ---------------------------------------------------------------------------
__global__ void __launch_bounds__(256) rms_rope(
    u16* Q, u16* K,
    const float* __restrict__ gq, const float* __restrict__ gk,
    const float* __restrict__ cf, const float* __restrict__ sf,
    const float* __restrict__ ch, const float* __restrict__ sh,
    const float* __restrict__ cw, const float* __restrict__ sw)
{
  __shared__ float red[2][4];
  const int s = blockIdx.x;
  const int t = threadIdx.x;
  const int wave = t >> 6, lane = t & 63;
  const size_t rowb = (size_t)s * DIM + t * 6;   // element index, even

  u32* q32 = (u32*)(Q + rowb);
  u32* k32 = (u32*)(K + rowb);
  u32 qw[3], kw[3];
#pragma unroll
  for (int j = 0; j < 3; ++j) { qw[j] = q32[j]; kw[j] = k32[j]; }

  float sq = 0.f, sk = 0.f;
#pragma unroll
  for (int j = 0; j < 3; ++j) {
    float a0 = b2f((u16)qw[j]), a1 = b2f((u16)(qw[j] >> 16));
    float b0 = b2f((u16)kw[j]), b1 = b2f((u16)(kw[j] >> 16));
    sq += a0 * a0 + a1 * a1;
    sk += b0 * b0 + b1 * b1;
  }
#pragma unroll
  for (int m = 1; m < 64; m <<= 1) {
    sq += __shfl_xor(sq, m, 64);
    sk += __shfl_xor(sk, m, 64);
  }
  if (lane == 0) { red[0][wave] = sq; red[1][wave] = sk; }
  __syncthreads();
  const float tq = red[0][0] + red[0][1] + red[0][2] + red[0][3];
  const float tk = red[1][0] + red[1][1] + red[1][2] + red[1][3];
  const float scq = rsqrtf(tq * (1.0f / DIM) + 1e-6f);
  const float sck = rsqrtf(tk * (1.0f / DIM) + 1e-6f);

  const int f  = s / (H_DIM * W_DIM);
  const int hh = (s / W_DIM) % H_DIM;
  const int w  = s % W_DIM;

#pragma unroll
  for (int j = 0; j < 3; ++j) {
    const int pi = t * 3 + j;       // global pair index 0..767
    const int c = pi & 63;          // rotary pair within head (C=64)
    float co, si;
    if (c < 22)      { co = cf[f * 22 + c];        si = sf[f * 22 + c]; }
    else if (c < 43) { co = ch[hh * 21 + c - 22];  si = sh[hh * 21 + c - 22]; }
    else             { co = cw[w * 21 + c - 43];   si = sw[w * 21 + c - 43]; }
    const int gi = 2 * pi;          // == head*128 + 2*c
    const float2 gqv = *(const float2*)&gq[gi];
    const float2 gkv = *(const float2*)&gk[gi];
    {
      float e = b2f((u16)qw[j])         * scq * gqv.x;
      float o = b2f((u16)(qw[j] >> 16)) * scq * gqv.y;
      q32[j] = (u32)f2bf(e * co - o * si) | ((u32)f2bf(e * si + o * co) << 16);
    }
    {
      float e = b2f((u16)kw[j])         * sck * gkv.x;
      float o = b2f((u16)(kw[j] >> 16)) * sck * gkv.y;
      k32[j] = (u32)f2bf(e * co - o * si) | ((u32)f2bf(e * si + o * co) << 16);
    }
  }
}

// ---------------------------------------------------------------------------
// V transpose: Vt[d][s] = V[s][d]  (bf16), 64x64 LDS tiles.
// ---------------------------------------------------------------------------
__global__ void __launch_bounds__(256) transpose_v(
    const u16* __restrict__ V, u16* __restrict__ Vt)
{
  __shared__ u16 tile[64][65];
  const int s0 = blockIdx.x * 64, d0 = blockIdx.y * 64;
  const int t = threadIdx.x;
#pragma unroll
  for (int i = 0; i < 16; ++i) {
    int idx = t + i * 256; int rr = idx >> 6, cc = idx & 63;
    tile[rr][cc] = V[(size_t)(s0 + rr) * DIM + d0 + cc];
  }
  __syncthreads();
#pragma unroll
  for (int i = 0; i < 16; ++i) {
    int idx = t + i * 256; int rr = idx >> 6, cc = idx & 63;
    Vt[(size_t)(d0 + rr) * S_LEN + s0 + cc] = tile[cc][rr];
  }
}

// ---------------------------------------------------------------------------
// Flash attention v11: K/V full double-buffer, ONE barrier per k-tile.
// Round-8 lesson: occupancy is hard-capped at 2 blocks/CU by the unified
// VGPR file (~230 live regs incl. 96-reg O accumulator) -- more blocks via
// nsplit=4 bought nothing and cost 2x partial traffic. So the residual ~22%
// idle (MfmaUtil 38.8 + VALUBusy 38.8) must come from within the block: the
// TWO vmcnt(0)-draining barriers per k-tile. Now Ks and Vs are both
// double-buffered (LDS 32->64 KB, still 2 blocks/CU = 128 <= 160 KB):
//   prologue: stage K,V(t0)->buf0; sync
//   loop:     stage K,V(t+1)->buf^1; QK(cur)->softmax->PV(cur); sync; cur^=1
// Safety (round-5-verified protocol): barrier at end of t-1 drains the
// staged loads of buf[cur] (syncthreads => vmcnt(0)) and orders staging
// into buf^1 after all t-1 reads of it.
// Geometry/softmax/P-path unchanged from the verified v9: mt=3, 504 blocks
// = 8 XCD x 63, nsplit=2, static-max softmax, permlane redistribution.
// ---------------------------------------------------------------------------
__global__ void __launch_bounds__(256, 2) attn_kernel(
    const u16* __restrict__ rq, const u16* __restrict__ rk,
    const u16* __restrict__ vt,
    u16* __restrict__ po, float* __restrict__ pl, int klen)
{
  __shared__ u16 Ks[2][64 * 128];    // 2 x 16 KB  [key][d]; slot(kr,kc) = chunk kc^(kr&15)
  __shared__ u16 Vs[2][128 * 64];    // 2 x 16 KB  [d][key]; slot(vd,vc) = chunk vc^(vd&7)

  // decode: 504 blocks = 8 xcd * 63; slice pinned to XCD = id&7
  const int id    = blockIdx.x;
  const int xcd   = id & 7;
  const int rest  = id >> 3;          // 0..62
  const int band  = rest / 21;        // 0..2
  const int slot  = rest - band * 21; // q-block 0..20
  const int slice = band * 8 + xcd;   // 0..23
  const int h     = slice % NH;
  const int split = slice / NH;
  const int k_begin = split * klen;
  const int k_end   = (k_begin + klen < S_LEN) ? (k_begin + klen) : S_LEN;
  const int qb = slot * 192;
  const int tid = threadIdx.x, wave = tid >> 6, lane = tid & 63;
  const int quad = lane >> 4, l15 = lane & 15;
  const int q0 = qb + wave * 48;

  const int kr_l   = (lane >> 4);          // K row within 4-row seg
  const int kc_l   = lane & 15;
  const int vdr_l  = (lane >> 3);          // V d-row within 8-row seg
  const int vc_l   = lane & 7;

  auto stageK = [&](int b, int kt) {
#pragma unroll
    for (int c = 0; c < 4; ++c) {
      const int seg = wave * 4 + c;
      const int kr = seg * 4 + kr_l;
      gld16(&rk[(size_t)(kt + kr) * DIM + h * HD + ((kc_l ^ (kr & 15)) << 3)],
            &Ks[b][seg * 512]);
    }
  };
  auto stageV = [&](int b, int kt) {
#pragma unroll
    for (int c = 0; c < 4; ++c) {
      const int seg = wave * 4 + c;
      const int vd = seg * 8 + vdr_l;
      gld16(&vt[(size_t)(h * HD + vd) * S_LEN + kt + ((vc_l ^ (vd & 7)) << 3)],
            &Vs[b][seg * 512]);
    }
  };

  // Q fragments (B-operand: n=query=l15, k=d=quad*8+j)
  short8 qf[3][4];
#pragma unroll
  for (int mt = 0; mt < 3; ++mt) {
    int row = q0 + mt * 16 + l15; if (row > S_LEN - 1) row = S_LEN - 1;
#pragma unroll
    for (int c = 0; c < 4; ++c)
      qf[mt][c] = *(const short8*)&rq[(size_t)row * DIM + h * HD + c * 32 + quad * 8];
  }

  float4v o[3][8] = {};                 // O^T: row=d(quad*4+r), col=query(l15)
  float l_[3] = {0.f, 0.f, 0.f};        // per-lane partial; reduced at epilogue

  const float SC = 0.08838834764831845f * 1.4426950408889634f;  // rsqrt(128)*log2(e)
  const float M0 = 20.0f;  // static max (log2 domain); hard bound is 16.4

  // ---- prologue: stage K(t0) + V(t0) into buf0 ----
  stageK(0, k_begin);
  stageV(0, k_begin);
  __syncthreads();   // drain tile 0

  int cur = 0;
  for (int kt = k_begin; kt < k_end; kt += 64) {
    // ---- prefetch next tile into the other buffer (stays in flight) ----
    if (kt + 64 < k_end) {
      stageK(cur ^ 1, kt + 64);
      stageV(cur ^ 1, kt + 64);
    }
    const char* KsC = (const char*)Ks[cur];
    const char* VsC = (const char*)Vs[cur];

    short8 pf[3][2];   // [mt][ko]: PV B-operand fragments

    // ---- two 32-key halves: QK (24 MFMA) -> exp -> pack -> permlane ----
#pragma unroll
    for (int half = 0; half < 2; ++half) {
      float4v sc[3][2] = {};   // [mt][nth]
      __builtin_amdgcn_s_setprio(1);
#pragma unroll
      for (int nth = 0; nth < 2; ++nth) {
        const int krow = (half * 2 + nth) * 16 + l15;
#pragma unroll
        for (int c = 0; c < 4; ++c) {
          const short8 kf = *(const short8*)(KsC + krow * 256 + (((c * 4 + quad) ^ l15) << 4));
#pragma unroll
          for (int mt = 0; mt < 3; ++mt)
            sc[mt][nth] = __builtin_amdgcn_mfma_f32_16x16x32_bf16(kf, qf[mt][c], sc[mt][nth], 0, 0, 0);
        }
      }
      __builtin_amdgcn_s_setprio(0);

#pragma unroll
      for (int mt = 0; mt < 3; ++mt) {
        u32 W[2][2];
#pragma unroll
        for (int nth = 0; nth < 2; ++nth) {
          const float p0 = __builtin_amdgcn_exp2f(fmaf(sc[mt][nth][0], SC, -M0));
          const float p1 = __builtin_amdgcn_exp2f(fmaf(sc[mt][nth][1], SC, -M0));
          const float p2 = __builtin_amdgcn_exp2f(fmaf(sc[mt][nth][2], SC, -M0));
          const float p3 = __builtin_amdgcn_exp2f(fmaf(sc[mt][nth][3], SC, -M0));
          l_[mt] += (p0 + p1) + (p2 + p3);
          W[nth][0] = pack2(p0, p1);
          W[nth][1] = pack2(p2, p3);
        }
        u32 w0, w1, w2, w3;
        plswap(W[0][0], W[1][0], w0, w2, lane);   // j2=0, j2=2 words
        plswap(W[0][1], W[1][1], w1, w3, lane);   // j2=1, j2=3 words
        union { u32 w[4]; short8 s; } cv;
        cv.w[0] = w0; cv.w[1] = w1; cv.w[2] = w2; cv.w[3] = w3;
        pf[mt][half] = cv.s;
      }
    }

    // ---- O^T += V^T · P^T : 48 MFMAs (vf shared across mt) ----
    __builtin_amdgcn_s_setprio(1);
#pragma unroll
    for (int dt = 0; dt < 8; ++dt) {
      const int drow = dt * 16 + l15;
#pragma unroll
      for (int ko = 0; ko < 2; ++ko) {
        const short8 vf = *(const short8*)(VsC + drow * 128 + (((ko * 4 + quad) ^ (l15 & 7)) << 4));
#pragma unroll
        for (int mt = 0; mt < 3; ++mt)
          o[mt][dt] = __builtin_amdgcn_mfma_f32_16x16x32_bf16(vf, pf[mt][ko], o[mt][dt], 0, 0, 0);
      }
    }
    __builtin_amdgcn_s_setprio(0);

    __syncthreads();   // drains prefetch of t+1 + all reads of buf[cur]
    cur ^= 1;
  }

  // ---- epilogue: reduce l across quads; unnormalized partial o + l ----
#pragma unroll
  for (int mt = 0; mt < 3; ++mt) {
    float t = l_[mt];
    t += __shfl_xor(t, 16, 64);
    t += __shfl_xor(t, 32, 64);
    l_[mt] = t;
  }
#pragma unroll
  for (int mt = 0; mt < 3; ++mt) {
    const int q = q0 + mt * 16 + l15;
    const bool valid = q < S_LEN;
    const size_t rbase = ((size_t)(split * NH + h) * S_LEN + q) * HD;
#pragma unroll
    for (int dt = 0; dt < 8; ++dt) {
      if (valid) {
        ushort4 pk;
        pk.x = f2bf(o[mt][dt][0]); pk.y = f2bf(o[mt][dt][1]);
        pk.z = f2bf(o[mt][dt][2]); pk.w = f2bf(o[mt][dt][3]);
        *(ushort4*)&po[rbase + dt * 16 + quad * 4] = pk;
      }
    }
    if (quad == 0 && valid)
      pl[(size_t)(split * NH + h) * S_LEN + q] = l_[mt];
  }
}

// ---------------------------------------------------------------------------
// Merge nsplit ksplit partials (shared static max -> plain sums).
// One wave per (h,q) row, 2 d-elems per lane.
// ---------------------------------------------------------------------------
__global__ void __launch_bounds__(256) attn_merge(
    const u16* __restrict__ po, const float* __restrict__ pl,
    u16* __restrict__ ao, int nsplit)
{
  const int gw = (blockIdx.x * 256 + threadIdx.x) >> 6;  // (h,q) row id
  const int lane = threadIdx.x & 63;
  const int h = gw / S_LEN;
  const int q = gw - h * S_LEN;
  float den = 0.f, a0 = 0.f, a1 = 0.f;
  for (int s = 0; s < nsplit; ++s) {
    const size_t r = (size_t)(s * NH + h) * S_LEN + q;
    den += pl[r];
    const ushort2 v = *(const ushort2*)&po[r * HD + lane * 2];
    a0 += b2f(v.x); a1 += b2f(v.y);
  }
  const float inv = (den > 0.f) ? (1.0f / den) : 0.f;
  ushort2 out;
  out.x = f2bf(a0 * inv);
  out.y = f2bf(a1 * inv);
  *(ushort2*)&ao[(size_t)q * DIM + h * HD + lane * 2] = out;
}

// ---------------------------------------------------------------------------
extern "C" void kernel_launch(void* const* d_in, const int* in_sizes, int n_in,
                              void* d_out, int out_size, void* d_ws, size_t ws_size,
                              hipStream_t stream) {
  const float* x  = (const float*)d_in[0];
  const float* Wq = (const float*)d_in[1];
  const float* bq = (const float*)d_in[2];
  const float* Wk = (const float*)d_in[3];
  const float* bk = (const float*)d_in[4];
  const float* Wv = (const float*)d_in[5];
  const float* bv = (const float*)d_in[6];
  const float* Wo = (const float*)d_in[7];
  const float* bo = (const float*)d_in[8];
  const float* gq = (const float*)d_in[9];
  const float* gk = (const float*)d_in[10];
  const float* cf = (const float*)d_in[11];
  const float* sf = (const float*)d_in[12];
  const float* ch = (const float*)d_in[13];
  const float* sh = (const float*)d_in[14];
  const float* cw = (const float*)d_in[15];
  const float* sw = (const float*)d_in[16];

  char* ws = (char*)d_ws;
  const size_t sz  = (size_t)S_LEN * DIM * 2;  // 12.39 MB per bf16 activation
  const size_t wsz = (size_t)DIM * DIM * 2;    // 4.72 MB per bf16 weight
  u16* Xb  = (u16*)(ws);               // x bf16; reused as Vt after gemm_qkv
  u16* Qb  = (u16*)(ws + sz);          // becomes rq after rms_rope; reused as Ao
  u16* Kb  = (u16*)(ws + 2 * sz);      // becomes rk
  u16* Vb  = (u16*)(ws + 3 * sz);
  u16* Wqb = (u16*)(ws + 4 * sz);      // dead after gemm_qkv_fused
  u16* Wkb = (u16*)(ws + 4 * sz + wsz);
  u16* Wvb = (u16*)(ws + 4 * sz + 2 * wsz);

  // ksplit partials overlay Wqb..Wvb (dead after gemm_qkv_fused); Wo-bf16
  // lives beyond the partial region. nsplit=2 (round-8 lesson: occupancy is
  // VGPR-capped, more splits only add traffic): 4sz + 2*(po+pl) + wsz = 79.5 MB.
  const int nsplit = 2;
  const int klen   = 2048;             // 64-aligned k-split
  const size_t po_one = (size_t)NH * S_LEN * HD * 2;   // 12.39 MB per split
  const size_t pl_one = (size_t)NH * S_LEN * 4;        // 193.5 KB per split
  char* pbase = ws + 4 * sz;
  u16*   po = (u16*)pbase;
  float* pl = (float*)(pbase + (size_t)nsplit * po_one);
  u16* Wob = (u16*)(ws + 4 * sz + (size_t)nsplit * (po_one + pl_one));
  u16* Vt  = Xb;
  u16* Ao  = Qb;  // rq is dead after attn_kernel; merge writes here

  cast_all<<<(NX4 + 4 * NW4) / 256, 256, 0, stream>>>(
      x, Wq, Wk, Wv, Wo, Xb, Wqb, Wkb, Wvb, Wob);

  gemm_qkv_fused<<<dim3(24, 32), 256, 0, stream>>>(
      Xb, Wqb, Wkb, Wvb, bq, bk, bv, Qb, Kb, Vb);

  rms_rope<<<S_LEN, 256, 0, stream>>>(Qb, Kb, gq, gk, cf, sf, ch, sh, cw, sw);
  transpose_v<<<dim3(63, 24), 256, 0, stream>>>(Vb, Vt);
  attn_kernel<<<504, 256, 0, stream>>>(Qb, Kb, Vt, po, pl, klen);
  attn_merge<<<(NH * S_LEN) / 4, 256, 0, stream>>>(po, pl, Ao, nsplit);
  gemm_wo<<<dim3(12, 32), 256, 0, stream>>>(Ao, Wob, bo, (float*)d_out);
}